// Round 4
// baseline (340.046 us; speedup 1.0000x reference)
//
#include <hip/hip_runtime.h>
#include <hip/hip_cooperative_groups.h>
#include <math.h>

namespace cg = cooperative_groups;

#define NN_ 256      // nodes per graph
#define BB_ 64       // batch
#define FF_ 5        // features
#define NE_ 65536    // NN_*NN_
#define NBF_ 320     // BB_*FF_ stacked batch*feature columns

// workspace layout in floats (~2.9 MB, L2-resident)
#define OFF_GA  0        // L_A = 0.1 I + 0.45 A^T     (row-major)
#define OFF_G1  65536    // from M0
#define OFF_G3  131072   // from M1
#define OFF_G5  196608   // from M2
#define OFF_XT  262144   // X^T: [node][b*5+f], 256 x 320
#define OFF_T2  344064   // G5*GA  (post-relu composed operator)
#define OFF_P   409600   // G3*GA
#define OFF_Z1  475136   // G1*XT, 256 x 320
#define OFF_Y3  557056   // relu(P*Z1)
#define OFF_O   638976   // T2*Y3
#define OFF_DIS 720896   // 256
#define OFF_LG  721152   // 3 logits

// 256x256x256 GEMM tile: 4 rows x 256 cols per block; thread = col.
// A-row reads wave-uniform float4; B reads coalesced; two acc sets for ILP.
__device__ __forceinline__ void gemm4_256(
    const float* __restrict__ A, const float* __restrict__ B,
    float* __restrict__ C, int i0, int j) {
  float acc0[4] = {0.f, 0.f, 0.f, 0.f};
  float acc1[4] = {0.f, 0.f, 0.f, 0.f};
#pragma unroll 2
  for (int k = 0; k < NN_; k += 8) {
    const float b0 = B[(k + 0) * NN_ + j];
    const float b1 = B[(k + 1) * NN_ + j];
    const float b2 = B[(k + 2) * NN_ + j];
    const float b3 = B[(k + 3) * NN_ + j];
    const float b4 = B[(k + 4) * NN_ + j];
    const float b5 = B[(k + 5) * NN_ + j];
    const float b6 = B[(k + 6) * NN_ + j];
    const float b7 = B[(k + 7) * NN_ + j];
#pragma unroll
    for (int r = 0; r < 4; ++r) {
      const float4 a0 = *(const float4*)(A + (i0 + r) * NN_ + k);
      const float4 a1 = *(const float4*)(A + (i0 + r) * NN_ + k + 4);
      acc0[r] += a0.x * b0 + a0.y * b1 + a0.z * b2 + a0.w * b3;
      acc1[r] += a1.x * b4 + a1.y * b5 + a1.z * b6 + a1.w * b7;
    }
  }
#pragma unroll
  for (int r = 0; r < 4; ++r) C[(i0 + r) * NN_ + j] = acc0[r] + acc1[r];
}

// 256x320x256 GEMM tile: 4 rows; col tid, plus col 256+tid for wave 0.
__device__ __forceinline__ void gemm4_320(
    const float* __restrict__ A, const float* __restrict__ B,
    float* __restrict__ C, int i0, int tid) {
  const int j = tid;
  const int j2 = 256 + (tid & 63);
  const bool two = (tid < 64);  // wave-uniform
  float acc[4] = {0.f, 0.f, 0.f, 0.f};
  float acc2[4] = {0.f, 0.f, 0.f, 0.f};
  for (int k = 0; k < NN_; k += 4) {
    const float b0 = B[(k + 0) * NBF_ + j];
    const float b1 = B[(k + 1) * NBF_ + j];
    const float b2 = B[(k + 2) * NBF_ + j];
    const float b3 = B[(k + 3) * NBF_ + j];
#pragma unroll
    for (int r = 0; r < 4; ++r) {
      const float4 av = *(const float4*)(A + (i0 + r) * NN_ + k);
      acc[r] += av.x * b0 + av.y * b1 + av.z * b2 + av.w * b3;
    }
    if (two) {
      const float c0 = B[(k + 0) * NBF_ + j2];
      const float c1 = B[(k + 1) * NBF_ + j2];
      const float c2 = B[(k + 2) * NBF_ + j2];
      const float c3 = B[(k + 3) * NBF_ + j2];
#pragma unroll
      for (int r = 0; r < 4; ++r) {
        const float4 av = *(const float4*)(A + (i0 + r) * NN_ + k);
        acc2[r] += av.x * c0 + av.y * c1 + av.z * c2 + av.w * c3;
      }
    }
  }
#pragma unroll
  for (int r = 0; r < 4; ++r) {
    C[(i0 + r) * NBF_ + j] = acc[r];
    if (two) C[(i0 + r) * NBF_ + j2] = acc2[r];
  }
}

// 1 row x 320 cols: col tid (+ col 256+tid for wave 0).
__device__ __forceinline__ void gemv_320(
    const float* __restrict__ A, const float* __restrict__ B,
    float* __restrict__ C, int i, int tid, bool relu) {
  const int j = tid;
  const int j2 = 256 + (tid & 63);
  const bool two = (tid < 64);
  float a_a = 0.f, a_b = 0.f, a2_a = 0.f, a2_b = 0.f;
#pragma unroll 2
  for (int k = 0; k < NN_; k += 8) {
    const float4 a0 = *(const float4*)(A + i * NN_ + k);
    const float4 a1 = *(const float4*)(A + i * NN_ + k + 4);
    a_a += a0.x * B[(k + 0) * NBF_ + j] + a0.y * B[(k + 1) * NBF_ + j] +
           a0.z * B[(k + 2) * NBF_ + j] + a0.w * B[(k + 3) * NBF_ + j];
    a_b += a1.x * B[(k + 4) * NBF_ + j] + a1.y * B[(k + 5) * NBF_ + j] +
           a1.z * B[(k + 6) * NBF_ + j] + a1.w * B[(k + 7) * NBF_ + j];
    if (two) {
      a2_a += a0.x * B[(k + 0) * NBF_ + j2] + a0.y * B[(k + 1) * NBF_ + j2] +
              a0.z * B[(k + 2) * NBF_ + j2] + a0.w * B[(k + 3) * NBF_ + j2];
      a2_b += a1.x * B[(k + 4) * NBF_ + j2] + a1.y * B[(k + 5) * NBF_ + j2] +
              a1.z * B[(k + 6) * NBF_ + j2] + a1.w * B[(k + 7) * NBF_ + j2];
    }
  }
  float y = a_a + a_b;
  if (relu) y = fmaxf(y, 0.f);
  C[i * NBF_ + j] = y;
  if (two) {
    float y2 = a2_a + a2_b;
    if (relu) y2 = fmaxf(y2, 0.f);
    C[i * NBF_ + j2] = y2;
  }
}

__global__ __launch_bounds__(256) void mega(
    const float* __restrict__ x0g, const float* __restrict__ p,
    const float* __restrict__ a_uc, const float* __restrict__ b_uc,
    const float* __restrict__ u_pi, const float* __restrict__ u_rb,
    const float* __restrict__ lin_w, const float* __restrict__ lin_b,
    const float* __restrict__ fc_w, const float* __restrict__ fc_b,
    float* __restrict__ ws, float* __restrict__ out) {
  cg::grid_group grid = cg::this_grid();
  const int blk = blockIdx.x, tid = threadIdx.x;
  __shared__ float sh[NN_];

  // ---------------- ph0a: dis (row reduce), XT stage, scalars ----------------
  {
    const int i = blk, j = tid;
    const int t = (i >= j) ? (i * (i + 1) / 2 + j) : (j * (j + 1) / 2 + i);
    const float w = p[t];
    sh[j] = fabsf(w);
    __syncthreads();
    for (int s = NN_ / 2; s > 0; s >>= 1) {
      if (j < s) sh[j] += sh[j + s];
      __syncthreads();
    }
    if (j == 0) {
      const float deg = sh[0];
      ws[OFF_DIS + i] = (deg > 0.0f) ? (1.0f / sqrtf(deg)) : 0.0f;
    }
    for (int tt = tid; tt < NBF_; tt += 256) {
      const int b = tt / FF_, f = tt - FF_ * b;
      ws[OFF_XT + i * NBF_ + tt] = x0g[b * (NN_ * FF_) + i * FF_ + f];
    }
    if (blk == 0 && tid == 0) {
      float kld_sum = 0.0f;
      const float euler = 0.577215664901532f;
      for (int l = 0; l < 3; ++l) {
        float au = a_uc[l]; if (au < -10.0f) au = -10.0f;
        float bu = b_uc[l]; if (bu < -10.0f) bu = -10.0f; if (bu > 50.0f) bu = 50.0f;
        const float a = log1pf(expf(au));
        const float b = log1pf(expf(bu));
        float up = u_pi[l];
        up = fminf(fmaxf(up, 1e-6f), 1.0f - 1e-6f);
        const float pi = powf(1.0f - powf(up, 1.0f / b), 1.0f / a);
        ws[OFF_LG + l] = logf(pi) - log1pf(-pi);
        out[193 + l] = pi;  // drop_rates
        float x = b, dg = 0.0f;
        while (x < 6.0f) { dg -= 1.0f / x; x += 1.0f; }
        const float inv = 1.0f / x, inv2 = inv * inv;
        dg += logf(x) - 0.5f * inv
              - inv2 * (1.0f / 12.0f - inv2 * (1.0f / 120.0f - inv2 * (1.0f / 252.0f)));
        kld_sum += (1.0f - 0.8f / a) * (-euler - dg - 1.0f / b)
                   + logf(a * b + 1e-10f) - logf(0.8f) - (b - 1.0f) / b;
      }
      out[192] = kld_sum;  // kld_loss
    }
  }
  grid.sync();

  // ---------------- ph0b: operators G (transposed scatter) ----------------
  {
    const int i = blk, j = tid;
    const float disi = ws[OFF_DIS + i];
    const float disj = ws[OFF_DIS + j];
    const float lg0 = ws[OFF_LG + 0];
    const float lg1 = ws[OFF_LG + 1];
    const float lg2 = ws[OFF_LG + 2];
    const int t = (i >= j) ? (i * (i + 1) / 2 + j) : (j * (j + 1) / 2 + i);
    const float w = p[t];
    const float adj = disi * w * disj;
    const float dlt = (i == j) ? 0.1f : 0.0f;
    const int tcol = j * NN_ + i;
    const int idx = i * NN_ + j;
    const float inv_temp = 1.0f / 0.6f;

    ws[OFF_GA + tcol] = 0.45f * adj + dlt;

    float u, v, z;
    u = fminf(fmaxf(u_rb[0 * NE_ + idx], 1e-6f), 1.0f - 1e-6f);
    v = (lg0 + logf(u) - log1pf(-u)) * inv_temp;
    z = 1.0f / (1.0f + expf(-v));
    ws[OFF_G1 + tcol] = 0.45f * z * adj + dlt;

    u = fminf(fmaxf(u_rb[1 * NE_ + idx], 1e-6f), 1.0f - 1e-6f);
    v = (lg1 + logf(u) - log1pf(-u)) * inv_temp;
    z = 1.0f / (1.0f + expf(-v));
    ws[OFF_G3 + tcol] = 0.45f * z * adj + dlt;

    u = fminf(fmaxf(u_rb[2 * NE_ + idx], 1e-6f), 1.0f - 1e-6f);
    v = (lg2 + logf(u) - log1pf(-u)) * inv_temp;
    z = 1.0f / (1.0f + expf(-v));
    ws[OFF_G5 + tcol] = 0.45f * z * adj + dlt;
  }
  grid.sync();

  // ---------------- ph1: T2 = G5*GA ; P = G3*GA ; Z1 = G1*XT ----------------
  {
    const int sel = blk >> 6, r = blk & 63;
    if (sel == 0)      gemm4_256(ws + OFF_G5, ws + OFF_GA, ws + OFF_T2, r * 4, tid);
    else if (sel == 1) gemm4_256(ws + OFF_G3, ws + OFF_GA, ws + OFF_P,  r * 4, tid);
    else if (sel == 2) gemm4_320(ws + OFF_G1, ws + OFF_XT, ws + OFF_Z1, r * 4, tid);
    // sel == 3: idle
  }
  grid.sync();

  // ---------------- ph2: Y3 = relu(P * Z1) ----------------
  gemv_320(ws + OFF_P, ws + OFF_Z1, ws + OFF_Y3, blk, tid, true);
  grid.sync();

  // ---------------- ph3: O = T2 * Y3 ----------------
  gemv_320(ws + OFF_T2, ws + OFF_Y3, ws + OFF_O, blk, tid, false);
  grid.sync();

  // ---------------- ph4: head (64 blocks) ----------------
  if (blk < BB_) {
    const float* __restrict__ O = ws + OFF_O;
    const int b = blk;
    const int k = tid & 127, seg = tid >> 7;
    const float lw0 = lin_w[0 * 128 + k];
    const float lw1 = lin_w[1 * 128 + k];
    const float lw2 = lin_w[2 * 128 + k];
    const float lw3 = lin_w[3 * 128 + k];
    const float lw4 = lin_w[4 * 128 + k];
    const float lb = lin_b[k];
    float acc = 0.f;
    const int j0 = seg * 128;
#pragma unroll 4
    for (int jj = j0; jj < j0 + 128; ++jj) {
      const float* __restrict__ o = O + jj * NBF_ + b * FF_;
      const float v = lb + lw0 * o[0] + lw1 * o[1] + lw2 * o[2] +
                      lw3 * o[3] + lw4 * o[4];
      acc += fmaxf(v, 0.f);
    }
    sh[seg * 128 + k] = acc;
    __syncthreads();
    if (tid < 128) sh[tid] += sh[128 + tid];  // pooled[k]
    __syncthreads();
    if (tid < 3) {
      float s = fc_b[tid];
      for (int kk = 0; kk < 128; ++kk) s += sh[kk] * fc_w[kk * 3 + tid];
      out[b * 3 + tid] = s;
    }
  }
}

// ---------------------------------------------------------------------------
extern "C" void kernel_launch(void* const* d_in, const int* in_sizes, int n_in,
                              void* d_out, int out_size, void* d_ws,
                              size_t ws_size, hipStream_t stream) {
  const float* x      = (const float*)d_in[0];
  const float* p      = (const float*)d_in[1];
  const float* a_uc   = (const float*)d_in[2];
  const float* b_uc   = (const float*)d_in[3];
  const float* u_pi   = (const float*)d_in[4];
  const float* u_rb   = (const float*)d_in[5];
  const float* lin_w  = (const float*)d_in[6];
  const float* lin_b  = (const float*)d_in[7];
  const float* fc_w   = (const float*)d_in[8];
  const float* fc_b   = (const float*)d_in[9];
  // d_in[10] edge_index, d_in[11] batch: fully deterministic, never read.
  float* out = (float*)d_out;
  float* ws  = (float*)d_ws;

  void* args[] = {(void*)&x,     (void*)&p,     (void*)&a_uc, (void*)&b_uc,
                  (void*)&u_pi,  (void*)&u_rb,  (void*)&lin_w, (void*)&lin_b,
                  (void*)&fc_w,  (void*)&fc_b,  (void*)&ws,    (void*)&out};
  hipLaunchCooperativeKernel((void*)mega, dim3(256), dim3(256), args, 0, stream);
}

// Round 5
// 163.972 us; speedup vs baseline: 2.0738x; 2.0738x over previous
//
#include <hip/hip_runtime.h>
#include <math.h>

#define NN_ 256      // nodes per graph
#define BB_ 64       // batch
#define FF_ 5        // features
#define NE_ 65536    // NN_*NN_

// workspace layout in floats (1 MB total, L2/L3-resident)
// Operator storage: SL[k][j] = L[j][k] = 0.1*(k==j) + 0.45*M[k][j]
// so a GEMV stage Y[j] = sum_k L[j,k] X[k] reads SL[k*256+j] coalesced.
#define OFF_SLA 0        // from adj (symmetric)
#define OFF_SL1 65536    // from z0*adj
#define OFF_SL3 131072   // from z1*adj
#define OFF_SL5 196608   // from z2*adj

// ---------------------------------------------------------------------------
// K_A: one kernel builds everything. Block i, thread j.
//  - dis[j] computed per-thread (256-iter |p| row sum; p is L1/L2-hot)
//  - logits per-thread (few transcendentals, no cross-thread dep)
//  - all four operators written coalesced at [i*256+j]
//  - block 0 / thread 0: kld_loss + drop_rates scalars
// ---------------------------------------------------------------------------
__global__ __launch_bounds__(256) void build_all(
    const float* __restrict__ p, const float* __restrict__ a_uc,
    const float* __restrict__ b_uc, const float* __restrict__ u_pi,
    const float* __restrict__ u_rb, float* __restrict__ ws,
    float* __restrict__ out) {
  const int i = blockIdx.x, j = threadIdx.x;

  // row-sum of |W[j,:]| -> dis_j, no cross-block dependency
  const int jj2 = j * (j + 1) / 2;
  float s = 0.f;
#pragma unroll 4
  for (int k = 0; k < NN_; ++k) {
    const int t = (k <= j) ? (jj2 + k) : (k * (k + 1) / 2 + j);
    s += fabsf(p[t]);
  }
  __shared__ float sh[NN_];
  sh[j] = s;
  __syncthreads();
  const float si = sh[i];
  const float disj = (s > 0.f) ? rsqrtf(s) : 0.f;
  const float disi = (si > 0.f) ? rsqrtf(si) : 0.f;

  const int tij = (i >= j) ? (i * (i + 1) / 2 + j) : (jj2 + i);
  const float w = p[tij];
  const float adj = disi * w * disj;
  const float dlt = (i == j) ? 0.1f : 0.0f;

  // per-thread logits (redundant but cheap; avoids a dependency)
  float lg[3];
#pragma unroll
  for (int l = 0; l < 3; ++l) {
    const float au = fmaxf(a_uc[l], -10.0f);
    const float bu = fminf(fmaxf(b_uc[l], -10.0f), 50.0f);
    const float a = log1pf(expf(au));
    const float b = log1pf(expf(bu));
    const float up = fminf(fmaxf(u_pi[l], 1e-6f), 1.0f - 1e-6f);
    const float pi = powf(1.0f - powf(up, 1.0f / b), 1.0f / a);
    lg[l] = logf(pi) - log1pf(-pi);
  }

  const int idx = i * NN_ + j;
  const float inv_temp = 1.0f / 0.6f;
  ws[OFF_SLA + idx] = 0.45f * adj + dlt;

  float u, v, z;
  u = fminf(fmaxf(u_rb[0 * NE_ + idx], 1e-6f), 1.0f - 1e-6f);
  v = (lg[0] + logf(u) - log1pf(-u)) * inv_temp;
  z = 1.0f / (1.0f + expf(-v));
  ws[OFF_SL1 + idx] = 0.45f * z * adj + dlt;

  u = fminf(fmaxf(u_rb[1 * NE_ + idx], 1e-6f), 1.0f - 1e-6f);
  v = (lg[1] + logf(u) - log1pf(-u)) * inv_temp;
  z = 1.0f / (1.0f + expf(-v));
  ws[OFF_SL3 + idx] = 0.45f * z * adj + dlt;

  u = fminf(fmaxf(u_rb[2 * NE_ + idx], 1e-6f), 1.0f - 1e-6f);
  v = (lg[2] + logf(u) - log1pf(-u)) * inv_temp;
  z = 1.0f / (1.0f + expf(-v));
  ws[OFF_SL5 + idx] = 0.45f * z * adj + dlt;

  if (i == 0 && j == 0) {
    float kld_sum = 0.0f;
    const float euler = 0.577215664901532f;
    for (int l = 0; l < 3; ++l) {
      const float au = fmaxf(a_uc[l], -10.0f);
      const float bu = fminf(fmaxf(b_uc[l], -10.0f), 50.0f);
      const float a = log1pf(expf(au));
      const float b = log1pf(expf(bu));
      const float up = fminf(fmaxf(u_pi[l], 1e-6f), 1.0f - 1e-6f);
      const float pi = powf(1.0f - powf(up, 1.0f / b), 1.0f / a);
      out[193 + l] = pi;  // drop_rates
      float x = b, dg = 0.0f;
      while (x < 6.0f) { dg -= 1.0f / x; x += 1.0f; }
      const float inv = 1.0f / x, inv2 = inv * inv;
      dg += logf(x) - 0.5f * inv
            - inv2 * (1.0f / 12.0f - inv2 * (1.0f / 120.0f - inv2 * (1.0f / 252.0f)));
      kld_sum += (1.0f - 0.8f / a) * (-euler - dg - 1.0f / b)
                 + logf(a * b + 1e-10f) - logf(0.8f) - (b - 1.0f) / b;
    }
    out[192] = kld_sum;  // kld_loss
  }
}

// ---------------------------------------------------------------------------
// K_C: per-batch chain. 64 blocks x 1024 threads. All 5 conv stages + head.
// X lives in LDS (ping-pong, padded rows of 8); operators read coalesced
// from global (L2/L3-resident, shared across blocks). Partial k-sums reduced
// through LDS. Head reads O straight from LDS.
// ---------------------------------------------------------------------------
__global__ __launch_bounds__(1024) void batch_chain(
    const float* __restrict__ x0g, const float* __restrict__ ws,
    const float* __restrict__ lin_w, const float* __restrict__ lin_b,
    const float* __restrict__ fc_w, const float* __restrict__ fc_b,
    float* __restrict__ out) {
  const int b = blockIdx.x, tid = threadIdx.x;
  __shared__ float xbuf[2][NN_ * 8];   // 16 KB
  __shared__ float part[4 * NN_ * 8];  // 32 KB (reused by head)
  float* Xc = xbuf[0];
  float* Xn = xbuf[1];

  // stage input x[b] (layout [b*256+i][5]) into padded LDS rows [i][8]
  for (int idx = tid; idx < NN_ * FF_; idx += 1024) {
    const int i = idx / 5, f = idx - 5 * i;
    Xc[i * 8 + f] = x0g[b * (NN_ * FF_) + idx];
  }
  __syncthreads();

  const int q = tid >> 8;      // k-quarter 0..3
  const int j = tid & 255;     // output node
  const int k0 = q * 64;

#pragma unroll
  for (int l = 0; l < 5; ++l) {
    const float* __restrict__ Op =
        ws + (l == 0 ? OFF_SL1 : l == 2 ? OFF_SL3 : l == 4 ? OFF_SL5 : OFF_SLA)
        + j;
    float4 a03 = {0.f, 0.f, 0.f, 0.f};
    float a4 = 0.f;
#pragma unroll 8
    for (int k = k0; k < k0 + 64; ++k) {
      const float w = Op[k * NN_];                      // coalesced global
      const float4 xv = *(const float4*)(Xc + k * 8);   // LDS broadcast
      const float x4 = Xc[k * 8 + 4];
      a03.x += w * xv.x; a03.y += w * xv.y;
      a03.z += w * xv.z; a03.w += w * xv.w;
      a4 += w * x4;
    }
    *(float4*)(part + tid * 8) = a03;   // part[q][j][0..3]
    part[tid * 8 + 4] = a4;
    __syncthreads();
    // combine quarters: 2048 padded entries (pad f=5..7 is garbage, never read)
    for (int idx = tid; idx < 2048; idx += 1024) {
      const float sum = part[idx] + part[2048 + idx] + part[4096 + idx] +
                        part[6144 + idx];
      float y = 0.1f * Xc[idx] + 0.45f * sum;
      if (l == 2) y = fmaxf(y, 0.f);
      Xn[idx] = y;
    }
    __syncthreads();
    float* t = Xc; Xc = Xn; Xn = t;
  }

  // head: Xc holds O (256 x 5, padded 8). relu(O@lin_w+lin_b) -> pool -> fc.
  const int k = tid & 127, seg = tid >> 7;  // 8 segs x 32 rows
  const float lw0 = lin_w[0 * 128 + k];
  const float lw1 = lin_w[1 * 128 + k];
  const float lw2 = lin_w[2 * 128 + k];
  const float lw3 = lin_w[3 * 128 + k];
  const float lw4 = lin_w[4 * 128 + k];
  const float lb = lin_b[k];
  float acc = 0.f;
  const int j0 = seg * 32;
#pragma unroll 4
  for (int jj = j0; jj < j0 + 32; ++jj) {
    const float4 ov = *(const float4*)(Xc + jj * 8);  // LDS broadcast
    const float o4 = Xc[jj * 8 + 4];
    const float v = lb + lw0 * ov.x + lw1 * ov.y + lw2 * ov.z +
                    lw3 * ov.w + lw4 * o4;
    acc += fmaxf(v, 0.f);
  }
  part[seg * 128 + k] = acc;
  __syncthreads();
  if (tid < 128) {
    float s = 0.f;
#pragma unroll
    for (int s8 = 0; s8 < 8; ++s8) s += part[s8 * 128 + tid];
    part[tid] = s;  // pooled[k]
  }
  __syncthreads();
  if (tid < 3) {
    float s = fc_b[tid];
    for (int kk = 0; kk < 128; ++kk) s += part[kk] * fc_w[kk * 3 + tid];
    out[b * 3 + tid] = s;
  }
}

// ---------------------------------------------------------------------------
extern "C" void kernel_launch(void* const* d_in, const int* in_sizes, int n_in,
                              void* d_out, int out_size, void* d_ws,
                              size_t ws_size, hipStream_t stream) {
  const float* x      = (const float*)d_in[0];
  const float* p      = (const float*)d_in[1];
  const float* a_uc   = (const float*)d_in[2];
  const float* b_uc   = (const float*)d_in[3];
  const float* u_pi   = (const float*)d_in[4];
  const float* u_rb   = (const float*)d_in[5];
  const float* lin_w  = (const float*)d_in[6];
  const float* lin_b  = (const float*)d_in[7];
  const float* fc_w   = (const float*)d_in[8];
  const float* fc_b   = (const float*)d_in[9];
  // d_in[10] edge_index, d_in[11] batch: fully deterministic, never read.
  float* out = (float*)d_out;
  float* ws  = (float*)d_ws;

  build_all<<<256, 256, 0, stream>>>(p, a_uc, b_uc, u_pi, u_rb, ws, out);
  batch_chain<<<64, 1024, 0, stream>>>(x, ws, lin_w, lin_b, fc_w, fc_b, out);
}

// Round 6
// 133.877 us; speedup vs baseline: 2.5400x; 1.2248x over previous
//
#include <hip/hip_runtime.h>
#include <math.h>

#define NN_ 256      // nodes per graph
#define BB_ 64       // batch
#define FF_ 5        // features
#define NE_ 65536    // NN_*NN_

// workspace layout in floats (~1 MB, L2/L3-resident)
// Operator storage: SL[k][j] = L[j][k] = 0.1*(k==j) + 0.45*M[k][j]
// so a GEMV stage Y[j] = sum_k L[j,k] X[k] reads SL[k*256+j] coalesced.
#define OFF_SLA 0        // from adj (symmetric)
#define OFF_SL1 65536    // from z0*adj
#define OFF_SL3 131072   // from z1*adj
#define OFF_SL5 196608   // from z2*adj
#define OFF_DIS 262144   // 256 floats
#define OFF_LG  262400   // 3 floats

// ---------------------------------------------------------------------------
// K1: block i computes dis_i = 1/sqrt(sum_k |W[i,k]|) via LDS tree reduction
// (ONE p-load per thread). Block 0 lane 0 adds the scalar tail:
// logits, kld_loss, drop_rates.
// ---------------------------------------------------------------------------
__global__ __launch_bounds__(256) void k_dis(
    const float* __restrict__ p, const float* __restrict__ a_uc,
    const float* __restrict__ b_uc, const float* __restrict__ u_pi,
    float* __restrict__ ws, float* __restrict__ out) {
  const int i = blockIdx.x, k = threadIdx.x;
  const int t = (i >= k) ? (i * (i + 1) / 2 + k) : (k * (k + 1) / 2 + i);
  __shared__ float sh[NN_];
  sh[k] = fabsf(p[t]);
  __syncthreads();
  for (int s = NN_ / 2; s > 0; s >>= 1) {
    if (k < s) sh[k] += sh[k + s];
    __syncthreads();
  }
  if (k == 0) {
    const float deg = sh[0];
    ws[OFF_DIS + i] = (deg > 0.0f) ? (1.0f / sqrtf(deg)) : 0.0f;
  }

  if (i == 0 && k == 0) {
    float kld_sum = 0.0f;
    const float euler = 0.577215664901532f;
    for (int l = 0; l < 3; ++l) {
      const float au = fmaxf(a_uc[l], -10.0f);
      const float bu = fminf(fmaxf(b_uc[l], -10.0f), 50.0f);
      const float a = log1pf(expf(au));
      const float b = log1pf(expf(bu));
      const float up = fminf(fmaxf(u_pi[l], 1e-6f), 1.0f - 1e-6f);
      const float pi = powf(1.0f - powf(up, 1.0f / b), 1.0f / a);
      ws[OFF_LG + l] = logf(pi) - log1pf(-pi);
      out[193 + l] = pi;  // drop_rates
      float x = b, dg = 0.0f;
      while (x < 6.0f) { dg -= 1.0f / x; x += 1.0f; }
      const float inv = 1.0f / x, inv2 = inv * inv;
      dg += logf(x) - 0.5f * inv
            - inv2 * (1.0f / 12.0f - inv2 * (1.0f / 120.0f - inv2 * (1.0f / 252.0f)));
      kld_sum += (1.0f - 0.8f / a) * (-euler - dg - 1.0f / b)
                 + logf(a * b + 1e-10f) - logf(0.8f) - (b - 1.0f) / b;
    }
    out[192] = kld_sum;  // kld_loss
  }
}

// ---------------------------------------------------------------------------
// K2: build the four operators. Block i, lane j: one p gather, coalesced
// u_rb reads, coalesced writes at [i*256+j]. dis/logits read from ws.
// ---------------------------------------------------------------------------
__global__ __launch_bounds__(256) void build_ops(
    const float* __restrict__ p, const float* __restrict__ u_rb,
    float* __restrict__ ws) {
  const int i = blockIdx.x, j = threadIdx.x;
  const float disi = ws[OFF_DIS + i];   // wave-uniform
  const float disj = ws[OFF_DIS + j];   // coalesced
  const float lg0 = ws[OFF_LG + 0];
  const float lg1 = ws[OFF_LG + 1];
  const float lg2 = ws[OFF_LG + 2];

  const int t = (i >= j) ? (i * (i + 1) / 2 + j) : (j * (j + 1) / 2 + i);
  const float w = p[t];
  const float adj = disi * w * disj;
  const float dlt = (i == j) ? 0.1f : 0.0f;
  const int idx = i * NN_ + j;
  const float inv_temp = 1.0f / 0.6f;

  ws[OFF_SLA + idx] = 0.45f * adj + dlt;

  float u, v, z;
  u = fminf(fmaxf(u_rb[0 * NE_ + idx], 1e-6f), 1.0f - 1e-6f);
  v = (lg0 + logf(u) - log1pf(-u)) * inv_temp;
  z = 1.0f / (1.0f + expf(-v));
  ws[OFF_SL1 + idx] = 0.45f * z * adj + dlt;

  u = fminf(fmaxf(u_rb[1 * NE_ + idx], 1e-6f), 1.0f - 1e-6f);
  v = (lg1 + logf(u) - log1pf(-u)) * inv_temp;
  z = 1.0f / (1.0f + expf(-v));
  ws[OFF_SL3 + idx] = 0.45f * z * adj + dlt;

  u = fminf(fmaxf(u_rb[2 * NE_ + idx], 1e-6f), 1.0f - 1e-6f);
  v = (lg2 + logf(u) - log1pf(-u)) * inv_temp;
  z = 1.0f / (1.0f + expf(-v));
  ws[OFF_SL5 + idx] = 0.45f * z * adj + dlt;
}

// ---------------------------------------------------------------------------
// K3: per-batch chain. 64 blocks x 1024 threads. All 5 conv stages + head.
// X lives in LDS (ping-pong, padded rows of 8); operators read coalesced
// from global (L2/L3-resident, shared across blocks). Partial k-sums reduced
// through LDS. Head reads O straight from LDS.
// ---------------------------------------------------------------------------
__global__ __launch_bounds__(1024) void batch_chain(
    const float* __restrict__ x0g, const float* __restrict__ ws,
    const float* __restrict__ lin_w, const float* __restrict__ lin_b,
    const float* __restrict__ fc_w, const float* __restrict__ fc_b,
    float* __restrict__ out) {
  const int b = blockIdx.x, tid = threadIdx.x;
  __shared__ float xbuf[2][NN_ * 8];   // 16 KB
  __shared__ float part[4 * NN_ * 8];  // 32 KB (reused by head)
  float* Xc = xbuf[0];
  float* Xn = xbuf[1];

  // stage input x[b] (layout [b*256+i][5]) into padded LDS rows [i][8]
  for (int idx = tid; idx < NN_ * FF_; idx += 1024) {
    const int i = idx / 5, f = idx - 5 * i;
    Xc[i * 8 + f] = x0g[b * (NN_ * FF_) + idx];
  }
  __syncthreads();

  const int q = tid >> 8;      // k-quarter 0..3
  const int j = tid & 255;     // output node
  const int k0 = q * 64;

#pragma unroll
  for (int l = 0; l < 5; ++l) {
    const float* __restrict__ Op =
        ws + (l == 0 ? OFF_SL1 : l == 2 ? OFF_SL3 : l == 4 ? OFF_SL5 : OFF_SLA)
        + j;
    float4 a03 = {0.f, 0.f, 0.f, 0.f};
    float a4 = 0.f;
#pragma unroll 8
    for (int k = k0; k < k0 + 64; ++k) {
      const float w = Op[k * NN_];                      // coalesced global
      const float4 xv = *(const float4*)(Xc + k * 8);   // LDS broadcast
      const float x4 = Xc[k * 8 + 4];
      a03.x += w * xv.x; a03.y += w * xv.y;
      a03.z += w * xv.z; a03.w += w * xv.w;
      a4 += w * x4;
    }
    *(float4*)(part + tid * 8) = a03;   // part[q][j][0..3]
    part[tid * 8 + 4] = a4;
    __syncthreads();
    // combine quarters: 2048 padded entries (pad f=5..7 garbage, never read)
    for (int idx = tid; idx < 2048; idx += 1024) {
      const float sum = part[idx] + part[2048 + idx] + part[4096 + idx] +
                        part[6144 + idx];
      float y = 0.1f * Xc[idx] + 0.45f * sum;
      if (l == 2) y = fmaxf(y, 0.f);
      Xn[idx] = y;
    }
    __syncthreads();
    float* t = Xc; Xc = Xn; Xn = t;
  }

  // head: Xc holds O (256 x 5, padded 8). relu(O@lin_w+lin_b) -> pool -> fc.
  const int k = tid & 127, seg = tid >> 7;  // 8 segs x 32 rows
  const float lw0 = lin_w[0 * 128 + k];
  const float lw1 = lin_w[1 * 128 + k];
  const float lw2 = lin_w[2 * 128 + k];
  const float lw3 = lin_w[3 * 128 + k];
  const float lw4 = lin_w[4 * 128 + k];
  const float lb = lin_b[k];
  float acc = 0.f;
  const int j0 = seg * 32;
#pragma unroll 4
  for (int jj = j0; jj < j0 + 32; ++jj) {
    const float4 ov = *(const float4*)(Xc + jj * 8);  // LDS broadcast
    const float o4 = Xc[jj * 8 + 4];
    const float v = lb + lw0 * ov.x + lw1 * ov.y + lw2 * ov.z +
                    lw3 * ov.w + lw4 * o4;
    acc += fmaxf(v, 0.f);
  }
  part[seg * 128 + k] = acc;
  __syncthreads();
  if (tid < 128) {
    float s = 0.f;
#pragma unroll
    for (int s8 = 0; s8 < 8; ++s8) s += part[s8 * 128 + tid];
    part[tid] = s;  // pooled[k]
  }
  __syncthreads();
  if (tid < 3) {
    float s = fc_b[tid];
    for (int kk = 0; kk < 128; ++kk) s += part[kk] * fc_w[kk * 3 + tid];
    out[b * 3 + tid] = s;
  }
}

// ---------------------------------------------------------------------------
extern "C" void kernel_launch(void* const* d_in, const int* in_sizes, int n_in,
                              void* d_out, int out_size, void* d_ws,
                              size_t ws_size, hipStream_t stream) {
  const float* x      = (const float*)d_in[0];
  const float* p      = (const float*)d_in[1];
  const float* a_uc   = (const float*)d_in[2];
  const float* b_uc   = (const float*)d_in[3];
  const float* u_pi   = (const float*)d_in[4];
  const float* u_rb   = (const float*)d_in[5];
  const float* lin_w  = (const float*)d_in[6];
  const float* lin_b  = (const float*)d_in[7];
  const float* fc_w   = (const float*)d_in[8];
  const float* fc_b   = (const float*)d_in[9];
  // d_in[10] edge_index, d_in[11] batch: fully deterministic, never read.
  float* out = (float*)d_out;
  float* ws  = (float*)d_ws;

  k_dis<<<256, 256, 0, stream>>>(p, a_uc, b_uc, u_pi, ws, out);
  build_ops<<<256, 256, 0, stream>>>(p, u_rb, ws);
  batch_chain<<<64, 1024, 0, stream>>>(x, ws, lin_w, lin_b, fc_w, fc_b, out);
}